// Round 1
// baseline (61.461 us; speedup 1.0000x reference)
//
#include <hip/hip_runtime.h>
#include <cfloat>

// DistLoss: out = sum_m min_{s,n} ||surfaces[s,n,:] - targets[m,:]||^2
// surfaces: [4,4096,3] f32 (flat SN=16384 points), targets: [16384,3] f32.
//
// Plan:
//  k1: grid (M/1024, 64). Each block: stage a 256-point surface chunk in LDS
//      (SoA, float4-readable), each thread owns T=4 targets in regs, computes
//      per-target min over the chunk -> wmin[chunk][m]  (4 MB in d_ws).
//  k2: 64 blocks x 256 thr: min over 64 chunks per target, block-sum -> part[64].
//  k3: 1 wave: sum part[64] -> out[0].
// No atomics -> deterministic. All ws locations written before read each call.

namespace {
constexpr int M   = 16384;   // targets
constexpr int SN  = 16384;   // 4 * 4096 surface points
constexpr int TPB = 256;
constexpr int T   = 4;                     // targets per thread
constexpr int TGT_PER_BLOCK = TPB * T;     // 1024
constexpr int NCHUNK = 64;
constexpr int CHUNK  = SN / NCHUNK;        // 256
}

__global__ __launch_bounds__(TPB) void dist_partial_min(
    const float* __restrict__ surf,   // [SN][3]
    const float* __restrict__ tgt,    // [M][3]
    float* __restrict__ wmin)         // [NCHUNK][M]
{
  __shared__ alignas(16) float sx[CHUNK];
  __shared__ alignas(16) float sy[CHUNK];
  __shared__ alignas(16) float sz[CHUNK];

  const int tid   = threadIdx.x;
  const int mbase = blockIdx.x * TGT_PER_BLOCK;
  const int cbase = blockIdx.y * CHUNK;

  // stage chunk (AoS global -> SoA LDS)
  for (int i = tid; i < CHUNK; i += TPB) {
    const float* s = surf + (size_t)(cbase + i) * 3;
    sx[i] = s[0]; sy[i] = s[1]; sz[i] = s[2];
  }

  float tx[T], ty[T], tz[T], mn[T];
#pragma unroll
  for (int j = 0; j < T; ++j) {
    const int m   = mbase + j * TPB + tid;
    const float* tp = tgt + (size_t)m * 3;
    tx[j] = tp[0]; ty[j] = tp[1]; tz[j] = tp[2];
    mn[j] = FLT_MAX;
  }
  __syncthreads();

  for (int p = 0; p < CHUNK; p += 4) {
    const float4 X = *reinterpret_cast<const float4*>(&sx[p]);
    const float4 Y = *reinterpret_cast<const float4*>(&sy[p]);
    const float4 Z = *reinterpret_cast<const float4*>(&sz[p]);
#pragma unroll
    for (int j = 0; j < T; ++j) {
      float dx, dy, dz;
      dx = X.x - tx[j]; dy = Y.x - ty[j]; dz = Z.x - tz[j];
      const float d0 = dx*dx + dy*dy + dz*dz;
      dx = X.y - tx[j]; dy = Y.y - ty[j]; dz = Z.y - tz[j];
      const float d1 = dx*dx + dy*dy + dz*dz;
      dx = X.z - tx[j]; dy = Y.z - ty[j]; dz = Z.z - tz[j];
      const float d2 = dx*dx + dy*dy + dz*dz;
      dx = X.w - tx[j]; dy = Y.w - ty[j]; dz = Z.w - tz[j];
      const float d3 = dx*dx + dy*dy + dz*dz;
      mn[j] = fminf(mn[j], fminf(fminf(d0, d1), fminf(d2, d3)));
    }
  }

#pragma unroll
  for (int j = 0; j < T; ++j)
    wmin[(size_t)blockIdx.y * M + mbase + j * TPB + tid] = mn[j];
}

__global__ __launch_bounds__(256) void dist_min_sum(
    const float* __restrict__ wmin,   // [NCHUNK][M]
    float* __restrict__ part)         // [64]
{
  const int tid = threadIdx.x;
  const int m   = blockIdx.x * 256 + tid;

  float mnv = FLT_MAX;
  for (int c = 0; c < NCHUNK; ++c)
    mnv = fminf(mnv, wmin[(size_t)c * M + m]);

  float sum = mnv;
  for (int off = 32; off; off >>= 1) sum += __shfl_down(sum, off, 64);

  __shared__ float red[4];
  if ((tid & 63) == 0) red[tid >> 6] = sum;
  __syncthreads();
  if (tid == 0) part[blockIdx.x] = red[0] + red[1] + red[2] + red[3];
}

__global__ __launch_bounds__(64) void dist_final(
    const float* __restrict__ part, float* __restrict__ out)
{
  float v = part[threadIdx.x];
  for (int off = 32; off; off >>= 1) v += __shfl_down(v, off, 64);
  if (threadIdx.x == 0) out[0] = v;
}

extern "C" void kernel_launch(void* const* d_in, const int* in_sizes, int n_in,
                              void* d_out, int out_size, void* d_ws, size_t ws_size,
                              hipStream_t stream) {
  const float* surf = (const float*)d_in[0];   // 4*4096*3
  const float* tgt  = (const float*)d_in[1];   // 16384*3
  float* out  = (float*)d_out;
  float* wmin = (float*)d_ws;                              // NCHUNK*M floats = 4 MB
  float* part = wmin + (size_t)NCHUNK * M;                 // 64 floats

  dim3 g1(M / TGT_PER_BLOCK, NCHUNK);
  dist_partial_min<<<g1, TPB, 0, stream>>>(surf, tgt, wmin);
  dist_min_sum<<<M / 256, 256, 0, stream>>>(wmin, part);
  dist_final<<<1, 64, 0, stream>>>(part, out);
}

// Round 2
// 39.200 us; speedup vs baseline: 1.5679x; 1.5679x over previous
//
#include <hip/hip_runtime.h>
#include <cfloat>

// DistLoss: out = sum_m min_{s,n} ||surfaces[s,n,:] - targets[m,:]||^2
// surfaces: [4,4096,3] f32 (flat SN=16384 points), targets: [16384,3] f32.
//
// R2: expanded-distance form (matches the JAX reference's own a2+b2-2ab):
//   d(m,p) = s2[p] + x[p]*(-2 tx[m]) + y[p]*(-2 ty[m]) + z[p]*(-2 tz[m])   (+ b2[m] after the min)
// -> 3 fma per pair, min3 over point-pairs -> 3.5 VALU inst/pair (was ~12).
// LDS holds float4(x,y,z,s2) per point: one broadcast ds_read_b128 feeds
// T=8 targets (24 fma). b2 added once per target after the point loop.
//
//  k1: grid (M/2048, 64), 256 thr, T=8 targets/thread, CHUNK=256 points.
//  k2: 64 blocks: min over 64 chunks per target, block-sum -> part[64].
//  k3: 1 wave: sum part[64] -> out[0].
// No atomics -> deterministic.

namespace {
constexpr int M   = 16384;   // targets
constexpr int SN  = 16384;   // 4 * 4096 surface points
constexpr int TPB = 256;
constexpr int T   = 8;                     // targets per thread
constexpr int TGT_PER_BLOCK = TPB * T;     // 2048
constexpr int NCHUNK = 64;
constexpr int CHUNK  = SN / NCHUNK;        // 256 == TPB
}

__global__ __launch_bounds__(TPB) void dist_partial_min(
    const float* __restrict__ surf,   // [SN][3]
    const float* __restrict__ tgt,    // [M][3]
    float* __restrict__ wmin)         // [NCHUNK][M]
{
  __shared__ alignas(16) float4 spt[CHUNK];   // (x, y, z, s2)

  const int tid   = threadIdx.x;
  const int mbase = blockIdx.x * TGT_PER_BLOCK;
  const int cbase = blockIdx.y * CHUNK;

  // stage chunk: point + its squared norm (CHUNK == TPB: one point/thread)
  {
    const float* s = surf + (size_t)(cbase + tid) * 3;
    const float x = s[0], y = s[1], z = s[2];
    spt[tid] = make_float4(x, y, z, fmaf(x, x, fmaf(y, y, z * z)));
  }

  float tx[T], ty[T], tz[T], b2[T], mn[T];
#pragma unroll
  for (int j = 0; j < T; ++j) {
    const int m     = mbase + j * TPB + tid;
    const float* tp = tgt + (size_t)m * 3;
    const float a = tp[0], b = tp[1], c = tp[2];
    tx[j] = -2.0f * a; ty[j] = -2.0f * b; tz[j] = -2.0f * c;
    b2[j] = fmaf(a, a, fmaf(b, b, c * c));
    mn[j] = FLT_MAX;
  }
  __syncthreads();

  for (int p = 0; p < CHUNK; p += 4) {
    const float4 P0 = spt[p + 0];
    const float4 P1 = spt[p + 1];
    const float4 P2 = spt[p + 2];
    const float4 P3 = spt[p + 3];
#pragma unroll
    for (int j = 0; j < T; ++j) {
      const float d0 = fmaf(P0.x, tx[j], fmaf(P0.y, ty[j], fmaf(P0.z, tz[j], P0.w)));
      const float d1 = fmaf(P1.x, tx[j], fmaf(P1.y, ty[j], fmaf(P1.z, tz[j], P1.w)));
      const float d2 = fmaf(P2.x, tx[j], fmaf(P2.y, ty[j], fmaf(P2.z, tz[j], P2.w)));
      const float d3 = fmaf(P3.x, tx[j], fmaf(P3.y, ty[j], fmaf(P3.z, tz[j], P3.w)));
      mn[j] = fminf(fminf(mn[j], d0), d1);   // v_min3_f32
      mn[j] = fminf(fminf(mn[j], d2), d3);   // v_min3_f32
    }
  }

#pragma unroll
  for (int j = 0; j < T; ++j)
    wmin[(size_t)blockIdx.y * M + mbase + j * TPB + tid] = mn[j] + b2[j];
}

__global__ __launch_bounds__(256) void dist_min_sum(
    const float* __restrict__ wmin,   // [NCHUNK][M]
    float* __restrict__ part)         // [64]
{
  const int tid = threadIdx.x;
  const int m   = blockIdx.x * 256 + tid;

  float mnv = FLT_MAX;
  for (int c = 0; c < NCHUNK; ++c)
    mnv = fminf(mnv, wmin[(size_t)c * M + m]);

  float sum = mnv;
  for (int off = 32; off; off >>= 1) sum += __shfl_down(sum, off, 64);

  __shared__ float red[4];
  if ((tid & 63) == 0) red[tid >> 6] = sum;
  __syncthreads();
  if (tid == 0) part[blockIdx.x] = red[0] + red[1] + red[2] + red[3];
}

__global__ __launch_bounds__(64) void dist_final(
    const float* __restrict__ part, float* __restrict__ out)
{
  float v = part[threadIdx.x];
  for (int off = 32; off; off >>= 1) v += __shfl_down(v, off, 64);
  if (threadIdx.x == 0) out[0] = v;
}

extern "C" void kernel_launch(void* const* d_in, const int* in_sizes, int n_in,
                              void* d_out, int out_size, void* d_ws, size_t ws_size,
                              hipStream_t stream) {
  const float* surf = (const float*)d_in[0];   // 4*4096*3
  const float* tgt  = (const float*)d_in[1];   // 16384*3
  float* out  = (float*)d_out;
  float* wmin = (float*)d_ws;                              // NCHUNK*M floats = 4 MB
  float* part = wmin + (size_t)NCHUNK * M;                 // 64 floats

  dim3 g1(M / TGT_PER_BLOCK, NCHUNK);
  dist_partial_min<<<g1, TPB, 0, stream>>>(surf, tgt, wmin);
  dist_min_sum<<<M / 256, 256, 0, stream>>>(wmin, part);
  dist_final<<<1, 64, 0, stream>>>(part, out);
}